// Round 13
// baseline (41.733 us; speedup 1.0000x reference)
//
#include <hip/hip_runtime.h>

// G=14, B=64, T=2048, H=6
#define Gc 14
#define Hc 6
#define NPc (64*2048)          // B*T points
#define LOG_2PI 1.8378770664093453f

typedef float v2f __attribute__((ext_vector_type(2)));

__device__ __forceinline__ float frsq(float x){ return __builtin_amdgcn_rsqf(x); }

// Pinned packed-FP32 (VOP3P): 2 IEEE f32 ops per instruction.
__device__ __forceinline__ v2f pk_mul(v2f a, v2f b){
    v2f d; asm("v_pk_mul_f32 %0, %1, %2" : "=v"(d) : "v"(a), "v"(b)); return d;
}
__device__ __forceinline__ v2f pk_fma(v2f a, v2f b, v2f c){
    v2f d; asm("v_pk_fma_f32 %0, %1, %2, %3" : "=v"(d) : "v"(a), "v"(b), "v"(c)); return d;
}

// DPP quad_perm broadcast of lane L's value to all 4 lanes of its quad.
template<int CTRL>
__device__ __forceinline__ float dppf(float x){
    union { float f; int i; } u; u.f = x;
    u.i = __builtin_amdgcn_update_dpp(0, u.i, CTRL, 0xF, 0xF, true);
    return u.f;
}
template<int L>
__device__ __forceinline__ float qbcast(float x){ return dppf<L * 0x55>(x); }

// Nontemporal stores: keep the 22 MB output stream out of L2/L3 (R11 win).
__device__ __forceinline__ void nt_store_v2f(float* p, v2f v){
    union { v2f f; unsigned long long u; } c; c.f = v;
    __builtin_nontemporal_store(c.u, (unsigned long long*)p);
}

// One sweep of N-1 chained gprods.
// Quad layout (1 point = 4 lanes; uniform v2f banks so one pk stream serves all):
//   L0: bank0=cur{0,1}, bank1=cur{4,5}
//   L1: bank0=cur{2,3}, bank1={b,b}      (b duplicated; rides the pk update)
//   L2: bank0=nxt{0,1}, bank1=nxt{4,5}
//   L3: bank0=nxt{2,3}, bank1={b,b}
// Head channel = comp C of bank B on owner lane L (phase1: cur -> L0/L1;
// phase2: nxt -> L2/L3), broadcast to the quad via DPP.
// Identities (|r*C|==1): x3 = a1*x1 + a2n*x2 ; x4 = s2*x1 + s1*x2, with
//   S=rsqrt(C1^2+C2^2), s1=C2*S, s2=C1*S, a1=copysign(s1,C1), a2n=-copysign(s2,C2).
// logC == 0 exactly -> dropped. Per gprod: 2 dpp + ~8 head ops + 8 pk ops.
template<int L, int B, int C, int N>
__device__ __forceinline__ void sweep(v2f (&st)[Gc][2]){
#pragma unroll
    for (int i = 0; i < N - 1; ++i){
        const float C1 = qbcast<L>(st[i][B][C]);
        const float C2 = qbcast<L>(st[i + 1][B][C]);
        const float S  = frsq(fmaf(C1, C1, C2 * C2));   // 1 transcendental per gprod
        const float s1 = C2 * S, s2 = C1 * S;
        const float a1 = copysignf(s1, C1), a2n = -copysignf(s2, C2);
        const v2f A1 = {a1, a1}, A2N = {a2n, a2n}, S1 = {s1, s1}, S2 = {s2, s2};
#pragma unroll
        for (int j = 0; j < 2; ++j){
            const v2f x = st[i][j], y = st[i + 1][j];
            st[i][j]     = pk_fma(x, A1, pk_mul(y, A2N));   // x3 -> slot i
            st[i + 1][j] = pk_fma(x, S2, pk_mul(y, S1));    // x4 -> slot i+1
        }
    }
}

// __launch_bounds__(256, N) caps VGPRs at ~256/N (empirical R4/R6/R12).
// N=4 -> 64-VGPR cap = 8 waves/SIMD tier. Grid: 131072 points x 4 lanes =
// 8192 waves = exactly 8/SIMD on 1024 SIMDs. State = 56 floats/lane, so the
// cap is ~honest (R4/R6 spill-stormed at 2-3x over cap; this is ~1.1x).
__global__ void __launch_bounds__(256, 4)
gaussmerge_kernel(const float* __restrict__ cur_in,
                  const float* __restrict__ nxt_in,
                  const float* __restrict__ b_in,
                  float* __restrict__ out)
{
    const int tid = threadIdx.x;
    const int l = tid & 3;                          // lane role in quad
    const int p = blockIdx.x * 64 + (tid >> 2);     // point index

    const float* arr   = (l < 2) ? cur_in : nxt_in;
    const float* baseA = arr + (size_t)p * Hc + ((l & 1) ? 2 : 0);
    const float* baseB = arr + (size_t)p * Hc + 4;
    const float* bp    = b_in + p;

    v2f st[Gc][2];
#pragma unroll
    for (int g = 0; g < Gc; ++g){
        const v2f A = *(const v2f*)(baseA + (size_t)g * (NPc * Hc));
        const v2f M = *(const v2f*)(baseB + (size_t)g * (NPc * Hc));  // cur45/nxt45 (L1/L3: dup of L0/L2 -> same addr, L1$ hit)
        const float bv = bp[(size_t)g * NPc];
        st[g][0] = A;
        st[g][1] = (l & 1) ? (v2f){bv, bv} : M;
    }

    float LC = 0.0f;   // log terms broadcast -> identical on all 4 lanes

    // ---- phase 1: head = cur[k]; n = 14-k ----
    sweep<0, 0, 0, 14>(st); LC -= __logf(fabsf(qbcast<0>(st[13][0][0])));
    sweep<0, 0, 1, 13>(st); LC -= __logf(fabsf(qbcast<0>(st[12][0][1])));
    sweep<1, 0, 0, 12>(st); LC -= __logf(fabsf(qbcast<1>(st[11][0][0])));
    sweep<1, 0, 1, 11>(st); LC -= __logf(fabsf(qbcast<1>(st[10][0][1])));
    sweep<0, 1, 0, 10>(st); LC -= __logf(fabsf(qbcast<0>(st[ 9][1][0])));
    sweep<0, 1, 1,  9>(st); LC -= __logf(fabsf(qbcast<0>(st[ 8][1][1])));

    // ---- phase 2: head = nxt[k]; n = 8-k; popped slot m = 7-k ----
    float* outN = out;                               // (6, B, T, H)
    float* outB = out + (size_t)Hc * NPc * Hc;       // (6, B, T)
    float* outL = outB + (size_t)Hc * NPc;           // (B, T)

#define PH2(K, L_, B_, C_, N_)                                                  \
    sweep<L_, B_, C_, N_>(st);                                                  \
    {                                                                           \
        constexpr int m = 7 - (K);                                              \
        float* o = outN + (size_t)(K) * (NPc * Hc) + (size_t)p * Hc;            \
        if (l == 2){                                                            \
            nt_store_v2f(o,     st[m][0]);    /* nxt{0,1} */                    \
            nt_store_v2f(o + 4, st[m][1]);    /* nxt{4,5} */                    \
        } else if (l == 3){                                                     \
            nt_store_v2f(o + 2, st[m][0]);    /* nxt{2,3} */                    \
        } else if (l == 1){                                                     \
            __builtin_nontemporal_store(st[m][1][0], outB + (size_t)(K) * NPc + p); \
        }                                                                       \
    }

    PH2(0, 2, 0, 0, 8)
    PH2(1, 2, 0, 1, 7)
    PH2(2, 3, 0, 0, 6)
    PH2(3, 3, 0, 1, 5)
    PH2(4, 2, 1, 0, 4)
    PH2(5, 2, 1, 1, 3)
#undef PH2

    // ---- epilogue: remaining biases (slots 0,1) live on L1/L3 bank1.x ----
    const float b0 = qbcast<1>(st[0][1][0]);
    const float b1 = qbcast<1>(st[1][1][0]);
    LC += -0.5f * (LOG_2PI + b0 * b0);
    LC += -0.5f * (LOG_2PI + b1 * b1);
    if (l == 0) __builtin_nontemporal_store(LC, outL + p);
}

extern "C" void kernel_launch(void* const* d_in, const int* in_sizes, int n_in,
                              void* d_out, int out_size, void* d_ws, size_t ws_size,
                              hipStream_t stream) {
    const float* cur = (const float*)d_in[0];
    const float* nxt = (const float*)d_in[1];
    const float* bia = (const float*)d_in[2];
    float* out = (float*)d_out;

    // 4 threads per point: 256-thread blocks cover 64 points each.
    dim3 grid((NPc * 4) / 256), block(256);
    gaussmerge_kernel<<<grid, block, 0, stream>>>(cur, nxt, bia, out);
}